// Round 1
// baseline (2805.194 us; speedup 1.0000x reference)
//
#include <hip/hip_runtime.h>
#include <math.h>

#define L 2048
#define BSZ 2
#define NH 16
#define DH 64
#define DM 1024
#define SCALE_F 0.125f

#define BI 32
#define BJ 64

// ---------------------------------------------------------------------------
// Generic K=1024 fp32 tiled GEMM: C = A @ B + bias, with output layout modes.
// A: [M][1024] row-major. B: [1024][1024] row-major. bias: [1024].
// mode 0: rows m=(i,b) b-fast -> out[(((b*NH+n)*L)+i)*DH+dh]  (q/k/v)
// mode 1: rows m=p           -> out[((n*L)+p)*DH+dh]          (r_k)
// mode 2: plain row-major     -> out[m*1024+col]              (attn_out)
// ---------------------------------------------------------------------------
__global__ __launch_bounds__(256)
void gemm_k1024(const float* __restrict__ A, const float* __restrict__ B,
                const float* __restrict__ bias, float* __restrict__ out, int mode)
{
    __shared__ float As[16][65];
    __shared__ float Bs[16][65];
    const int t  = threadIdx.x;
    const int bm = blockIdx.x * 64;
    const int bn = blockIdx.y * 64;
    const int tx = t & 15, ty = t >> 4;
    float acc[4][4] = {};

    const int la_row = t >> 2;        // 0..63
    const int la_k   = (t & 3) << 2;  // 0,4,8,12
    const int lb_k   = t >> 4;        // 0..15
    const int lb_col = (t & 15) << 2; // 0..60

    for (int k0 = 0; k0 < 1024; k0 += 16) {
        float4 av = *reinterpret_cast<const float4*>(A + (size_t)(bm + la_row) * 1024 + k0 + la_k);
        As[la_k + 0][la_row] = av.x;
        As[la_k + 1][la_row] = av.y;
        As[la_k + 2][la_row] = av.z;
        As[la_k + 3][la_row] = av.w;
        float4 bv = *reinterpret_cast<const float4*>(B + (size_t)(k0 + lb_k) * 1024 + bn + lb_col);
        Bs[lb_k][lb_col + 0] = bv.x;
        Bs[lb_k][lb_col + 1] = bv.y;
        Bs[lb_k][lb_col + 2] = bv.z;
        Bs[lb_k][lb_col + 3] = bv.w;
        __syncthreads();
        #pragma unroll
        for (int kk = 0; kk < 16; ++kk) {
            float a[4], b[4];
            #pragma unroll
            for (int r = 0; r < 4; ++r) a[r] = As[kk][ty * 4 + r];
            #pragma unroll
            for (int c = 0; c < 4; ++c) b[c] = Bs[kk][tx * 4 + c];
            #pragma unroll
            for (int r = 0; r < 4; ++r)
                #pragma unroll
                for (int c = 0; c < 4; ++c)
                    acc[r][c] += a[r] * b[c];
        }
        __syncthreads();
    }

    #pragma unroll
    for (int r = 0; r < 4; ++r) {
        #pragma unroll
        for (int c = 0; c < 4; ++c) {
            int m   = bm + ty * 4 + r;
            int col = bn + tx * 4 + c;
            float val = acc[r][c] + bias[col];
            if (mode == 0) {
                int i = m >> 1, b = m & 1;
                int n = col >> 6, dh = col & 63;
                out[(((size_t)(b * NH + n) * L) + i) * DH + dh] = val;
            } else if (mode == 1) {
                int n = col >> 6, dh = col & 63;
                out[((size_t)n * L + m) * DH + dh] = val;
            } else {
                out[(size_t)m * 1024 + col] = val;
            }
        }
    }
}

// ---------------------------------------------------------------------------
// Fused causal flash attention with Transformer-XL relative shift.
// After rel_shift+mask, surviving entries:
//   S[i,j] = SCALE*( q[i]·k[j] + rwb·k[j] + q[i]·rk[L-1+j-i] + rrb·rk[L-1+j-i] )
// for j<=i.  rwb·k and rrb·rk are per-column scalars (ck/cr).
// One block: BI=32 query rows of one (b,n); loops j-tiles of BJ=64.
// ---------------------------------------------------------------------------
__global__ __launch_bounds__(256)
void attn_fused(const float* __restrict__ qg, const float* __restrict__ kg,
                const float* __restrict__ vg, const float* __restrict__ rkg,
                const float* __restrict__ rwb, const float* __restrict__ rrb,
                float* __restrict__ av_out)
{
    __shared__ float qt[BI][DH + 1];
    __shared__ float kt[BJ][DH + 1];
    __shared__ float vt[BJ][DH + 1];
    __shared__ float rkt[BI + BJ][DH + 1];   // band: BI+BJ-1 = 95 rows used
    __shared__ float pt[BI][BJ + 1];
    __shared__ float ck[BJ];
    __shared__ float cr[BI + BJ];
    __shared__ float rwbs[DH], rrbs[DH];

    const int t  = threadIdx.x;
    const int bh = blockIdx.y;        // b*NH + n
    const int n  = bh & (NH - 1);
    const int b  = bh >> 4;
    const int i0 = blockIdx.x * BI;

    const float* qb  = qg  + (size_t)bh * L * DH;
    const float* kb  = kg  + (size_t)bh * L * DH;
    const float* vb  = vg  + (size_t)bh * L * DH;
    const float* rkb = rkg + (size_t)n  * L * DH;

    if (t < DH)            rwbs[t]      = rwb[n * DH + t];
    else if (t < 2 * DH)   rrbs[t - DH] = rrb[n * DH + (t - DH)];

    for (int l = t; l < BI * DH; l += 256) {
        int r = l >> 6, d = l & 63;
        qt[r][d] = qb[(size_t)(i0 + r) * DH + d];
    }

    const int tx = t & 15, ty = t >> 4;
    const int r0 = ty * 2, r1 = ty * 2 + 1;
    float m_run[2] = {-INFINITY, -INFINITY};
    float l_run[2] = {0.f, 0.f};
    float O[2][4] = {};

    for (int j0 = 0; j0 <= i0 + BI - 1; j0 += BJ) {
        __syncthreads();  // qt visible (1st iter); LDS safe to overwrite (later iters)
        for (int l = t; l < BJ * DH; l += 256) {
            int r = l >> 6, d = l & 63;
            kt[r][d] = kb[(size_t)(j0 + r) * DH + d];
            vt[r][d] = vb[(size_t)(j0 + r) * DH + d];
        }
        const int p_start = (L - 1) + j0 - (i0 + BI - 1);   // >= 0 always
        for (int l = t; l < (BI + BJ - 1) * DH; l += 256) {
            int r = l >> 6, d = l & 63;
            int p = p_start + r;
            if (p > L - 1) p = L - 1;     // rows with p>=L are masked anyway
            rkt[r][d] = rkb[(size_t)p * DH + d];
        }
        __syncthreads();
        if (t < BJ) {
            float s = 0.f;
            for (int d = 0; d < DH; ++d) s += rwbs[d] * kt[t][d];
            ck[t] = s;
        } else if (t < BJ + (BI + BJ - 1)) {
            int pp = t - BJ;
            float s = 0.f;
            for (int d = 0; d < DH; ++d) s += rrbs[d] * rkt[pp][d];
            cr[pp] = s;
        }
        __syncthreads();

        float s_ac[2][4] = {};
        float s_bd[2][4] = {};
        for (int kk = 0; kk < DH; ++kk) {
            float q0 = qt[r0][kk], q1 = qt[r1][kk];
            #pragma unroll
            for (int c = 0; c < 4; ++c) {
                int jj = tx * 4 + c;
                float kv = kt[jj][kk];
                s_ac[0][c] += q0 * kv;
                s_ac[1][c] += q1 * kv;
                float rv0 = rkt[jj + (BI - 1) - r0][kk];
                float rv1 = rkt[jj + (BI - 1) - r1][kk];
                s_bd[0][c] += q0 * rv0;
                s_bd[1][c] += q1 * rv1;
            }
        }

        #pragma unroll
        for (int rr = 0; rr < 2; ++rr) {
            const int ri = ty * 2 + rr;
            const int i_glob = i0 + ri;
            float sv[4];
            float rmax = -INFINITY;
            #pragma unroll
            for (int c = 0; c < 4; ++c) {
                int jj = tx * 4 + c;
                int j_glob = j0 + jj;
                float s = SCALE_F * (s_ac[rr][c] + s_bd[rr][c] + ck[jj] + cr[jj + (BI - 1) - ri]);
                if (j_glob > i_glob) s = -INFINITY;
                sv[c] = s;
                rmax = fmaxf(rmax, s);
            }
            #pragma unroll
            for (int off = 1; off < 16; off <<= 1)
                rmax = fmaxf(rmax, __shfl_xor(rmax, off));
            float newm = fmaxf(m_run[rr], rmax);
            float sc = expf(m_run[rr] - newm);
            float rsum = 0.f;
            #pragma unroll
            for (int c = 0; c < 4; ++c) {
                float p = expf(sv[c] - newm);   // exp(-inf)=0 handles mask
                pt[ri][tx * 4 + c] = p;
                rsum += p;
            }
            #pragma unroll
            for (int off = 1; off < 16; off <<= 1)
                rsum += __shfl_xor(rsum, off);
            l_run[rr] = l_run[rr] * sc + rsum;
            m_run[rr] = newm;
            #pragma unroll
            for (int c = 0; c < 4; ++c) O[rr][c] *= sc;
        }
        __syncthreads();

        for (int jj = 0; jj < BJ; ++jj) {
            float p0 = pt[r0][jj], p1 = pt[r1][jj];
            #pragma unroll
            for (int c = 0; c < 4; ++c) {
                float vv = vt[jj][tx * 4 + c];
                O[0][c] += p0 * vv;
                O[1][c] += p1 * vv;
            }
        }
    }

    #pragma unroll
    for (int rr = 0; rr < 2; ++rr) {
        int i_glob = i0 + ty * 2 + rr;
        float inv = 1.0f / l_run[rr];
        #pragma unroll
        for (int c = 0; c < 4; ++c) {
            av_out[(size_t)(i_glob * BSZ + b) * (NH * DH) + n * DH + tx * 4 + c] = O[rr][c] * inv;
        }
    }
}

// ---------------------------------------------------------------------------
// Fused residual + LayerNorm: out[row] = LN(w[row] + attn_out[row]) * g + b
// One 256-thread block per row of 1024.
// ---------------------------------------------------------------------------
__global__ __launch_bounds__(256)
void ln_fused(const float* __restrict__ w, const float* __restrict__ ao,
              const float* __restrict__ g, const float* __restrict__ bb,
              float* __restrict__ out)
{
    const int row = blockIdx.x;
    const float* wr = w  + (size_t)row * DM;
    const float* ar = ao + (size_t)row * DM;
    const int t = threadIdx.x;
    float x[4];
    float s = 0.f;
    #pragma unroll
    for (int j = 0; j < 4; ++j) {
        int c = t + j * 256;
        x[j] = wr[c] + ar[c];
        s += x[j];
    }
    __shared__ float red[4];
    #pragma unroll
    for (int off = 1; off < 64; off <<= 1) s += __shfl_xor(s, off);
    int wid = t >> 6, lane = t & 63;
    if (lane == 0) red[wid] = s;
    __syncthreads();
    float mu = (red[0] + red[1] + red[2] + red[3]) * (1.0f / DM);
    float ss = 0.f;
    #pragma unroll
    for (int j = 0; j < 4; ++j) { float d = x[j] - mu; ss += d * d; }
    #pragma unroll
    for (int off = 1; off < 64; off <<= 1) ss += __shfl_xor(ss, off);
    __syncthreads();
    if (lane == 0) red[wid] = ss;
    __syncthreads();
    float var = (red[0] + red[1] + red[2] + red[3]) * (1.0f / DM);
    float rstd = rsqrtf(var + 1e-5f);
    #pragma unroll
    for (int j = 0; j < 4; ++j) {
        int c = t + j * 256;
        out[(size_t)row * DM + c] = (x[j] - mu) * rstd * g[c] + bb[c];
    }
}

extern "C" void kernel_launch(void* const* d_in, const int* in_sizes, int n_in,
                              void* d_out, int out_size, void* d_ws, size_t ws_size,
                              hipStream_t stream)
{
    (void)in_sizes; (void)n_in; (void)out_size; (void)ws_size;
    const float* w   = (const float*)d_in[0];
    const float* r   = (const float*)d_in[1];
    const float* rwb = (const float*)d_in[2];
    const float* rrb = (const float*)d_in[3];
    const float* Wq  = (const float*)d_in[4];
    const float* bq  = (const float*)d_in[5];
    const float* Wk  = (const float*)d_in[6];
    const float* bk  = (const float*)d_in[7];
    const float* Wv  = (const float*)d_in[8];
    const float* bv  = (const float*)d_in[9];
    const float* Wr  = (const float*)d_in[10];
    const float* br  = (const float*)d_in[11];
    const float* Wo  = (const float*)d_in[12];
    const float* bo  = (const float*)d_in[13];
    const float* lng = (const float*)d_in[14];
    const float* lnb = (const float*)d_in[15];
    float* out = (float*)d_out;

    float* ws    = (float*)d_ws;
    float* q_ws  = ws;
    float* k_ws  = q_ws  + (size_t)BSZ * NH * L * DH;   //  4M floats
    float* v_ws  = k_ws  + (size_t)BSZ * NH * L * DH;
    float* rk_ws = v_ws  + (size_t)BSZ * NH * L * DH;
    float* av_ws = rk_ws + (size_t)NH * L * DH;         //  2M floats
    float* ao_ws = av_ws + (size_t)L * BSZ * NH * DH;   //  4M floats
    // total ws use: 23,068,672 floats = 92.3 MB

    dim3 blk(256);
    gemm_k1024<<<dim3(64, 16), blk, 0, stream>>>(w, Wq, bq, q_ws, 0);
    gemm_k1024<<<dim3(64, 16), blk, 0, stream>>>(w, Wk, bk, k_ws, 0);
    gemm_k1024<<<dim3(64, 16), blk, 0, stream>>>(w, Wv, bv, v_ws, 0);
    gemm_k1024<<<dim3(32, 16), blk, 0, stream>>>(r, Wr, br, rk_ws, 1);
    attn_fused<<<dim3(L / BI, BSZ * NH), blk, 0, stream>>>(q_ws, k_ws, v_ws, rk_ws, rwb, rrb, av_ws);
    gemm_k1024<<<dim3(64, 16), blk, 0, stream>>>(av_ws, Wo, bo, ao_ws, 2);
    ln_fused<<<dim3(L * BSZ), blk, 0, stream>>>(w, ao_ws, lng, lnb, out);
}

// Round 3
// 1161.620 us; speedup vs baseline: 2.4149x; 2.4149x over previous
//
#include <hip/hip_runtime.h>
#include <math.h>

#define L 2048
#define BSZ 2
#define NH 16
#define DH 64
#define DM 1024
#define SCALE_F 0.125f

typedef __attribute__((ext_vector_type(8))) __bf16 bf16x8;
typedef __attribute__((ext_vector_type(4))) float f32x4;

// ---------------------------------------------------------------------------
// Generic K=1024 fp32 tiled GEMM: C = A @ B + bias, with output layout modes.
// mode 0: bf16 out, rows m=(i,b) b-fast -> out[(((b*NH+n)*L)+i)*DH+dh]  (k/v)
// mode 1: bf16 out, rows m=p            -> out[((n*L)+p)*DH+dh]         (r_k)
// mode 2: fp32 out, plain row-major     -> out[m*1024+col]              (attn_out)
// mode 3: dual bf16 out: out=val+rwb[col], out2=val+rrb[col], layout of mode 0 (q)
// ---------------------------------------------------------------------------
__global__ __launch_bounds__(256)
void gemm_k1024(const float* __restrict__ A, const float* __restrict__ B,
                const float* __restrict__ bias, void* __restrict__ out,
                void* __restrict__ out2, const float* __restrict__ rwbf,
                const float* __restrict__ rrbf, int mode)
{
    __shared__ float As[16][65];
    __shared__ float Bs[16][65];
    const int t  = threadIdx.x;
    const int bm = blockIdx.x * 64;
    const int bn = blockIdx.y * 64;
    const int tx = t & 15, ty = t >> 4;
    float acc[4][4] = {};

    const int la_row = t >> 2;
    const int la_k   = (t & 3) << 2;
    const int lb_k   = t >> 4;
    const int lb_col = (t & 15) << 2;

    for (int k0 = 0; k0 < 1024; k0 += 16) {
        float4 av = *reinterpret_cast<const float4*>(A + (size_t)(bm + la_row) * 1024 + k0 + la_k);
        As[la_k + 0][la_row] = av.x;
        As[la_k + 1][la_row] = av.y;
        As[la_k + 2][la_row] = av.z;
        As[la_k + 3][la_row] = av.w;
        float4 bv = *reinterpret_cast<const float4*>(B + (size_t)(k0 + lb_k) * 1024 + bn + lb_col);
        Bs[lb_k][lb_col + 0] = bv.x;
        Bs[lb_k][lb_col + 1] = bv.y;
        Bs[lb_k][lb_col + 2] = bv.z;
        Bs[lb_k][lb_col + 3] = bv.w;
        __syncthreads();
        #pragma unroll
        for (int kk = 0; kk < 16; ++kk) {
            float a[4], b[4];
            #pragma unroll
            for (int r = 0; r < 4; ++r) a[r] = As[kk][ty * 4 + r];
            #pragma unroll
            for (int c = 0; c < 4; ++c) b[c] = Bs[kk][tx * 4 + c];
            #pragma unroll
            for (int r = 0; r < 4; ++r)
                #pragma unroll
                for (int c = 0; c < 4; ++c)
                    acc[r][c] += a[r] * b[c];
        }
        __syncthreads();
    }

    #pragma unroll
    for (int r = 0; r < 4; ++r) {
        #pragma unroll
        for (int c = 0; c < 4; ++c) {
            int m   = bm + ty * 4 + r;
            int col = bn + tx * 4 + c;
            float val = acc[r][c] + bias[col];
            if (mode == 0) {
                int i = m >> 1, b = m & 1;
                int n = col >> 6, dh = col & 63;
                ((__bf16*)out)[(((size_t)(b * NH + n) * L) + i) * DH + dh] = (__bf16)val;
            } else if (mode == 1) {
                int n = col >> 6, dh = col & 63;
                ((__bf16*)out)[((size_t)n * L + m) * DH + dh] = (__bf16)val;
            } else if (mode == 2) {
                ((float*)out)[(size_t)m * 1024 + col] = val;
            } else {
                int i = m >> 1, b = m & 1;
                int n = col >> 6, dh = col & 63;
                size_t idx = (((size_t)(b * NH + n) * L) + i) * DH + dh;
                ((__bf16*)out )[idx] = (__bf16)(val + rwbf[col]);
                ((__bf16*)out2)[idx] = (__bf16)(val + rrbf[col]);
            }
        }
    }
}

// ---------------------------------------------------------------------------
// MFMA flash attention with TXL relative shift.
// Block = 4 waves, 64 query rows (wave w owns rows [i0+16w, +16)), j-tiles of 64.
// S[i][j] = SCALE*( qw[i]·k[j] + qr[i]·rk[L-1+j-i] ),  j<=i
// BD computed as band GEMM Dband[ri][c]=qr·rk[p0+c], shifted via LDS read.
// ---------------------------------------------------------------------------
__global__ __launch_bounds__(256)
void attn_mfma(const __bf16* __restrict__ qwg, const __bf16* __restrict__ qrg,
               const __bf16* __restrict__ kg,  const __bf16* __restrict__ vg,
               const __bf16* __restrict__ rkg, float* __restrict__ av_out)
{
    __shared__ __bf16 kt [64][72];
    __shared__ __bf16 vtT[64][72];     // transposed: vtT[d][j]
    __shared__ __bf16 rkt[128][72];    // band rows (127 used + 1 guard)
    __shared__ __bf16 pt [4][16][72];  // per-wave P tile
    __shared__ float  dband[4][16][84];

    const int t    = threadIdx.x;
    const int w    = t >> 6;
    const int lane = t & 63;
    const int row16 = lane & 15;
    const int kgrp  = lane >> 4;

    const int bh = blockIdx.y;
    const int n  = bh & (NH - 1);
    const int b  = bh >> 4;
    const int i0 = (gridDim.x - 1 - blockIdx.x) * 64;   // long blocks first
    const int i0w = i0 + w * 16;

    const __bf16* qwb = qwg + (size_t)bh * L * DH;
    const __bf16* qrb = qrg + (size_t)bh * L * DH;
    const __bf16* kb  = kg  + (size_t)bh * L * DH;
    const __bf16* vb  = vg  + (size_t)bh * L * DH;
    const __bf16* rkb = rkg + (size_t)n  * L * DH;

    // Q fragments in registers (loaded once). A-frag: lane holds row (lane&15),
    // 8 contiguous k-elems at (lane>>4)*8 + 32*ks.
    bf16x8 qwf[2], qrf[2];
    #pragma unroll
    for (int ks = 0; ks < 2; ++ks) {
        size_t off = (size_t)(i0w + row16) * DH + kgrp * 8 + ks * 32;
        qwf[ks] = *reinterpret_cast<const bf16x8*>(qwb + off);
        qrf[ks] = *reinterpret_cast<const bf16x8*>(qrb + off);
    }

    float m_run[4], l_run[4];
    f32x4 O[4];
    #pragma unroll
    for (int r = 0; r < 4; ++r) { m_run[r] = -INFINITY; l_run[r] = 0.f; }
    #pragma unroll
    for (int cb = 0; cb < 4; ++cb) O[cb] = (f32x4){0.f, 0.f, 0.f, 0.f};

    for (int j0 = 0; j0 <= i0 + 63; j0 += 64) {
        __syncthreads();   // previous iteration's LDS reads complete

        // ---- stage K tile + transposed V tile ----
        {
            int j  = t >> 2;
            int d0 = (t & 3) * 16;
            bf16x8 ka = *reinterpret_cast<const bf16x8*>(kb + (size_t)(j0 + j) * DH + d0);
            bf16x8 kb2 = *reinterpret_cast<const bf16x8*>(kb + (size_t)(j0 + j) * DH + d0 + 8);
            *reinterpret_cast<bf16x8*>(&kt[j][d0])     = ka;
            *reinterpret_cast<bf16x8*>(&kt[j][d0 + 8]) = kb2;
            bf16x8 va = *reinterpret_cast<const bf16x8*>(vb + (size_t)(j0 + j) * DH + d0);
            bf16x8 vb2 = *reinterpret_cast<const bf16x8*>(vb + (size_t)(j0 + j) * DH + d0 + 8);
            #pragma unroll
            for (int kk = 0; kk < 8; ++kk) {
                vtT[d0 + kk][j]     = va[kk];
                vtT[d0 + 8 + kk][j] = vb2[kk];
            }
        }
        // ---- stage rk band (128 rows, p clamped; clamped rows are masked cols) ----
        {
            const int p0 = (L - 1) + j0 - (i0 + 63);
            for (int l = t; l < 128 * 4; l += 256) {
                int rr = l >> 2;
                int d0 = (l & 3) * 16;
                int p  = p0 + rr; if (p > L - 1) p = L - 1;
                bf16x8 ra = *reinterpret_cast<const bf16x8*>(rkb + (size_t)p * DH + d0);
                bf16x8 rb2 = *reinterpret_cast<const bf16x8*>(rkb + (size_t)p * DH + d0 + 8);
                *reinterpret_cast<bf16x8*>(&rkt[rr][d0])     = ra;
                *reinterpret_cast<bf16x8*>(&rkt[rr][d0 + 8]) = rb2;
            }
        }
        __syncthreads();

        // ---- AC = QW · K^T  (4 col-blocks x 2 k-steps) ----
        f32x4 ac[4];
        #pragma unroll
        for (int cb = 0; cb < 4; ++cb) ac[cb] = (f32x4){0.f, 0.f, 0.f, 0.f};
        #pragma unroll
        for (int ks = 0; ks < 2; ++ks)
            #pragma unroll
            for (int cb = 0; cb < 4; ++cb) {
                bf16x8 kf = *reinterpret_cast<const bf16x8*>(&kt[16 * cb + row16][kgrp * 8 + ks * 32]);
                ac[cb] = __builtin_amdgcn_mfma_f32_16x16x32_bf16(qwf[ks], kf, ac[cb], 0, 0, 0);
            }

        // ---- Dband = QR · RK_band^T (5 col-blocks covering 80 band cols) ----
        {
            f32x4 db[5];
            #pragma unroll
            for (int cb = 0; cb < 5; ++cb) db[cb] = (f32x4){0.f, 0.f, 0.f, 0.f};
            const int bandoff = 48 - 16 * w;   // wave's band start within rkt
            #pragma unroll
            for (int ks = 0; ks < 2; ++ks)
                #pragma unroll
                for (int cb = 0; cb < 5; ++cb) {
                    bf16x8 rf = *reinterpret_cast<const bf16x8*>(&rkt[bandoff + 16 * cb + row16][kgrp * 8 + ks * 32]);
                    db[cb] = __builtin_amdgcn_mfma_f32_16x16x32_bf16(qrf[ks], rf, db[cb], 0, 0, 0);
                }
            #pragma unroll
            for (int cb = 0; cb < 5; ++cb)
                #pragma unroll
                for (int r = 0; r < 4; ++r)
                    dband[w][kgrp * 4 + r][16 * cb + row16] = db[cb][r];
        }

        // ---- softmax (online), shift-read of BD, write P (bf16) ----
        #pragma unroll
        for (int r = 0; r < 4; ++r) {
            const int ri = kgrp * 4 + r;
            const int i_glob = i0w + ri;
            float sv[4];
            float rmax = -INFINITY;
            #pragma unroll
            for (int cb = 0; cb < 4; ++cb) {
                int jj = 16 * cb + row16;
                float s = SCALE_F * (ac[cb][r] + dband[w][ri][jj + 15 - ri]);
                if (j0 + jj > i_glob) s = -INFINITY;
                sv[cb] = s;
                rmax = fmaxf(rmax, s);
            }
            #pragma unroll
            for (int off = 1; off < 16; off <<= 1)
                rmax = fmaxf(rmax, __shfl_xor(rmax, off));
            float newm = fmaxf(m_run[r], rmax);
            float sc = expf(m_run[r] - newm);
            float rsum = 0.f;
            #pragma unroll
            for (int cb = 0; cb < 4; ++cb) {
                float p = expf(sv[cb] - newm);
                pt[w][ri][16 * cb + row16] = (__bf16)p;
                rsum += p;
            }
            #pragma unroll
            for (int off = 1; off < 16; off <<= 1)
                rsum += __shfl_xor(rsum, off);
            l_run[r] = l_run[r] * sc + rsum;
            m_run[r] = newm;
            #pragma unroll
            for (int cb = 0; cb < 4; ++cb) O[cb][r] *= sc;
        }

        // ---- O += P · V  (A=P from pt, B=V from vtT; per-wave private LDS) ----
        #pragma unroll
        for (int ks = 0; ks < 2; ++ks) {
            bf16x8 pf = *reinterpret_cast<const bf16x8*>(&pt[w][row16][kgrp * 8 + ks * 32]);
            #pragma unroll
            for (int cb = 0; cb < 4; ++cb) {
                bf16x8 vf = *reinterpret_cast<const bf16x8*>(&vtT[16 * cb + row16][kgrp * 8 + ks * 32]);
                O[cb] = __builtin_amdgcn_mfma_f32_16x16x32_bf16(pf, vf, O[cb], 0, 0, 0);
            }
        }
    }

    // ---- epilogue: normalize and write attn_vec rows [i*BSZ+b][n*64+d] ----
    #pragma unroll
    for (int r = 0; r < 4; ++r) {
        const int i_glob = i0w + kgrp * 4 + r;
        const float inv = 1.0f / l_run[r];
        #pragma unroll
        for (int cb = 0; cb < 4; ++cb) {
            av_out[(size_t)(i_glob * BSZ + b) * (NH * DH) + n * DH + 16 * cb + row16] = O[cb][r] * inv;
        }
    }
}

// ---------------------------------------------------------------------------
// Fused residual + LayerNorm
// ---------------------------------------------------------------------------
__global__ __launch_bounds__(256)
void ln_fused(const float* __restrict__ w, const float* __restrict__ ao,
              const float* __restrict__ g, const float* __restrict__ bb,
              float* __restrict__ out)
{
    const int row = blockIdx.x;
    const float* wr = w  + (size_t)row * DM;
    const float* ar = ao + (size_t)row * DM;
    const int t = threadIdx.x;
    float x[4];
    float s = 0.f;
    #pragma unroll
    for (int j = 0; j < 4; ++j) {
        int c = t + j * 256;
        x[j] = wr[c] + ar[c];
        s += x[j];
    }
    __shared__ float red[4];
    #pragma unroll
    for (int off = 1; off < 64; off <<= 1) s += __shfl_xor(s, off);
    int wid = t >> 6, lane = t & 63;
    if (lane == 0) red[wid] = s;
    __syncthreads();
    float mu = (red[0] + red[1] + red[2] + red[3]) * (1.0f / DM);
    float ss = 0.f;
    #pragma unroll
    for (int j = 0; j < 4; ++j) { float d = x[j] - mu; ss += d * d; }
    #pragma unroll
    for (int off = 1; off < 64; off <<= 1) ss += __shfl_xor(ss, off);
    __syncthreads();
    if (lane == 0) red[wid] = ss;
    __syncthreads();
    float var = (red[0] + red[1] + red[2] + red[3]) * (1.0f / DM);
    float rstd = rsqrtf(var + 1e-5f);
    #pragma unroll
    for (int j = 0; j < 4; ++j) {
        int c = t + j * 256;
        out[(size_t)row * DM + c] = (x[j] - mu) * rstd * g[c] + bb[c];
    }
}

extern "C" void kernel_launch(void* const* d_in, const int* in_sizes, int n_in,
                              void* d_out, int out_size, void* d_ws, size_t ws_size,
                              hipStream_t stream)
{
    (void)in_sizes; (void)n_in; (void)out_size; (void)ws_size;
    const float* w   = (const float*)d_in[0];
    const float* r   = (const float*)d_in[1];
    const float* rwb = (const float*)d_in[2];
    const float* rrb = (const float*)d_in[3];
    const float* Wq  = (const float*)d_in[4];
    const float* bq  = (const float*)d_in[5];
    const float* Wk  = (const float*)d_in[6];
    const float* bk  = (const float*)d_in[7];
    const float* Wv  = (const float*)d_in[8];
    const float* bv  = (const float*)d_in[9];
    const float* Wr  = (const float*)d_in[10];
    const float* br  = (const float*)d_in[11];
    const float* Wo  = (const float*)d_in[12];
    const float* bo  = (const float*)d_in[13];
    const float* lng = (const float*)d_in[14];
    const float* lnb = (const float*)d_in[15];
    float* out = (float*)d_out;

    const size_t NQ = (size_t)BSZ * NH * L * DH;   // 4.19M elems
    char* wsb = (char*)d_ws;
    __bf16* qw_ws = (__bf16*)wsb;                      wsb += NQ * 2;
    __bf16* qr_ws = (__bf16*)wsb;                      wsb += NQ * 2;
    __bf16* k_ws  = (__bf16*)wsb;                      wsb += NQ * 2;
    __bf16* v_ws  = (__bf16*)wsb;                      wsb += NQ * 2;
    __bf16* rk_ws = (__bf16*)wsb;                      wsb += (size_t)NH * L * DH * 2;
    float*  av_ws = (float*)wsb;                       wsb += NQ * 4;
    float*  ao_ws = (float*)wsb;                       // + NQ*4

    dim3 blk(256);
    gemm_k1024<<<dim3(64, 16), blk, 0, stream>>>(w, Wq, bq, qw_ws, qr_ws, rwb, rrb, 3);
    gemm_k1024<<<dim3(64, 16), blk, 0, stream>>>(w, Wk, bk, k_ws, nullptr, nullptr, nullptr, 0);
    gemm_k1024<<<dim3(64, 16), blk, 0, stream>>>(w, Wv, bv, v_ws, nullptr, nullptr, nullptr, 0);
    gemm_k1024<<<dim3(32, 16), blk, 0, stream>>>(r, Wr, br, rk_ws, nullptr, nullptr, nullptr, 1);
    attn_mfma<<<dim3(L / 64, BSZ * NH), blk, 0, stream>>>(qw_ws, qr_ws, k_ws, v_ws, rk_ws, av_ws);
    gemm_k1024<<<dim3(64, 16), blk, 0, stream>>>(av_ws, Wo, bo, ao_ws, nullptr, nullptr, nullptr, 2);
    ln_fused<<<dim3(L * BSZ), blk, 0, stream>>>(w, ao_ws, lng, lnb, out);
}

// Round 5
// 522.353 us; speedup vs baseline: 5.3703x; 2.2238x over previous
//
#include <hip/hip_runtime.h>
#include <math.h>

#define L 2048
#define BSZ 2
#define NH 16
#define DH 64
#define DM 1024
#define GK 1024
#define SCALE_F 0.125f

typedef __attribute__((ext_vector_type(8))) __bf16 bf16x8;
typedef __attribute__((ext_vector_type(4))) __bf16 bf16x4;
typedef __attribute__((ext_vector_type(4))) float f32x4;

// ---------------------------------------------------------------------------
// cast fp32 -> bf16, vectorized (float4 in, bf16x4 out)
// ---------------------------------------------------------------------------
__global__ __launch_bounds__(256)
void cast_f32_bf16(const float* __restrict__ src, __bf16* __restrict__ dst, int n4)
{
    int i = blockIdx.x * 256 + threadIdx.x;
    int stride = gridDim.x * 256;
    for (; i < n4; i += stride) {
        float4 v = reinterpret_cast<const float4*>(src)[i];
        bf16x4 o = { (__bf16)v.x, (__bf16)v.y, (__bf16)v.z, (__bf16)v.w };
        reinterpret_cast<bf16x4*>(dst)[i] = o;
    }
}

// ---------------------------------------------------------------------------
// Transpose 5x [1024x1024] fp32 -> bf16 transposed (rows of dst = cols of src)
// ---------------------------------------------------------------------------
__global__ __launch_bounds__(256)
void transpose_w5(const float* s0, const float* s1, const float* s2,
                  const float* s3, const float* s4,
                  __bf16* d0, __bf16* d1, __bf16* d2, __bf16* d3, __bf16* d4)
{
    const float* srcs[5] = { s0, s1, s2, s3, s4 };
    __bf16*      dsts[5] = { d0, d1, d2, d3, d4 };
    const float* src = srcs[blockIdx.z];
    __bf16*      dst = dsts[blockIdx.z];
    __shared__ float tile[32][33];
    const int tx = threadIdx.x & 31, ty = threadIdx.x >> 5;   // 32 x 8
    const int x0 = blockIdx.x * 32, y0 = blockIdx.y * 32;
    #pragma unroll
    for (int i = 0; i < 32; i += 8)
        tile[ty + i][tx] = src[(size_t)(y0 + ty + i) * 1024 + x0 + tx];
    __syncthreads();
    #pragma unroll
    for (int i = 0; i < 32; i += 8)
        dst[(size_t)(x0 + ty + i) * 1024 + y0 + tx] = (__bf16)tile[tx][ty + i];
}

// ---------------------------------------------------------------------------
// bf16 MFMA GEMM, m97 structure: 128x128 tile, BK=64, 4 waves, global_load_lds.
// C[row][col] = sum_k A[row][k] * Bt[col][k]  (Bt = B^T, rows are output cols)
// mode 0 (QKV): col in [0,3072): which=col>>10, c=col&1023, n=c>>6, dh=c&63,
//               i=row>>1, b=row&1 -> idx=(((b*NH+n)*L)+i)*DH+dh
//               which 0: o0[idx]=val+b0+rwb, o1[idx]=val+b0+rrb; 1: o2=val+b1; 2: o3=val+b2
// mode 1 (RK):  n=col>>6, dh=col&63 -> o0[(n*L+row)*DH+dh] = val+b0[col]
// mode 2 (O):   of[row*DM+col] = val + b0[col]   (fp32)
// ---------------------------------------------------------------------------
__global__ __launch_bounds__(256)
void gemm_bf16(const __bf16* __restrict__ A, const __bf16* __restrict__ Bt, int mode,
               __bf16* __restrict__ o0, __bf16* __restrict__ o1,
               __bf16* __restrict__ o2, __bf16* __restrict__ o3,
               const float* __restrict__ b0, const float* __restrict__ b1,
               const float* __restrict__ b2, const float* __restrict__ rwbf,
               const float* __restrict__ rrbf, float* __restrict__ of)
{
    __shared__ __bf16 As[128 * 64];
    __shared__ __bf16 Bs[128 * 64];

    const int t    = threadIdx.x;
    const int w    = t >> 6;
    const int lane = t & 63;
    const int row16 = lane & 15;
    const int kgrp  = lane >> 4;
    const int wr = w >> 1, wc = w & 1;

    const int bm = blockIdx.x * 128;
    const int bn = blockIdx.y * 128;

    f32x4 acc[4][4];
    #pragma unroll
    for (int mi = 0; mi < 4; ++mi)
        #pragma unroll
        for (int ni = 0; ni < 4; ++ni)
            acc[mi][ni] = (f32x4){0.f, 0.f, 0.f, 0.f};

    for (int k0 = 0; k0 < GK; k0 += 64) {
        __syncthreads();   // previous iteration's LDS reads complete
        #pragma unroll
        for (int it = 0; it < 4; ++it) {
            const int lin = (it * 256 + t) * 16;   // byte within 16KB tile
            const int row = lin >> 7;              // /128B per row
            const int kb  = lin & 127;
            const char* ga = (const char*)(A + (size_t)(bm + row) * GK + k0) + kb;
            __builtin_amdgcn_global_load_lds(
                (const __attribute__((address_space(1))) void*)ga,
                (__attribute__((address_space(3))) void*)((char*)As + lin), 16, 0, 0);
            const char* gb = (const char*)(Bt + (size_t)(bn + row) * GK + k0) + kb;
            __builtin_amdgcn_global_load_lds(
                (const __attribute__((address_space(1))) void*)gb,
                (__attribute__((address_space(3))) void*)((char*)Bs + lin), 16, 0, 0);
        }
        __syncthreads();   // drains vmcnt before barrier

        #pragma unroll
        for (int ks = 0; ks < 2; ++ks) {
            bf16x8 af[4], bfr[4];
            #pragma unroll
            for (int mi = 0; mi < 4; ++mi)
                af[mi] = *reinterpret_cast<const bf16x8*>(
                    &As[(wr * 64 + mi * 16 + row16) * 64 + kgrp * 8 + ks * 32]);
            #pragma unroll
            for (int ni = 0; ni < 4; ++ni)
                bfr[ni] = *reinterpret_cast<const bf16x8*>(
                    &Bs[(wc * 64 + ni * 16 + row16) * 64 + kgrp * 8 + ks * 32]);
            #pragma unroll
            for (int mi = 0; mi < 4; ++mi)
                #pragma unroll
                for (int ni = 0; ni < 4; ++ni)
                    acc[mi][ni] = __builtin_amdgcn_mfma_f32_16x16x32_bf16(
                        af[mi], bfr[ni], acc[mi][ni], 0, 0, 0);
        }
    }

    #pragma unroll
    for (int mi = 0; mi < 4; ++mi) {
        #pragma unroll
        for (int ni = 0; ni < 4; ++ni) {
            #pragma unroll
            for (int r = 0; r < 4; ++r) {
                const int row = bm + wr * 64 + mi * 16 + kgrp * 4 + r;
                const int col = bn + wc * 64 + ni * 16 + row16;
                const float val = acc[mi][ni][r];
                if (mode == 0) {
                    const int which = col >> 10, c = col & 1023;
                    const int n = c >> 6, dh = c & 63;
                    const int i = row >> 1, b = row & 1;
                    const size_t idx = (((size_t)(b * NH + n) * L) + i) * DH + dh;
                    if (which == 0) {
                        const float v0 = val + b0[c];
                        o0[idx] = (__bf16)(v0 + rwbf[c]);
                        o1[idx] = (__bf16)(v0 + rrbf[c]);
                    } else if (which == 1) {
                        o2[idx] = (__bf16)(val + b1[c]);
                    } else {
                        o3[idx] = (__bf16)(val + b2[c]);
                    }
                } else if (mode == 1) {
                    const int n = col >> 6, dh = col & 63;
                    o0[((size_t)n * L + row) * DH + dh] = (__bf16)(val + b0[col]);
                } else {
                    of[(size_t)row * DM + col] = val + b0[col];
                }
            }
        }
    }
}

// ---------------------------------------------------------------------------
// MFMA flash attention with TXL relative shift (unchanged from round 3 except
// bf16 output for the o-projection GEMM).
// ---------------------------------------------------------------------------
__global__ __launch_bounds__(256)
void attn_mfma(const __bf16* __restrict__ qwg, const __bf16* __restrict__ qrg,
               const __bf16* __restrict__ kg,  const __bf16* __restrict__ vg,
               const __bf16* __restrict__ rkg, __bf16* __restrict__ av_out)
{
    __shared__ __bf16 kt [64][72];
    __shared__ __bf16 vtT[64][72];
    __shared__ __bf16 rkt[128][72];
    __shared__ __bf16 pt [4][16][72];
    __shared__ float  dband[4][16][84];

    const int t    = threadIdx.x;
    const int w    = t >> 6;
    const int lane = t & 63;
    const int row16 = lane & 15;
    const int kgrp  = lane >> 4;

    const int bh = blockIdx.y;
    const int n  = bh & (NH - 1);
    const int b  = bh >> 4;
    const int i0 = (gridDim.x - 1 - blockIdx.x) * 64;
    const int i0w = i0 + w * 16;

    const __bf16* qwb = qwg + (size_t)bh * L * DH;
    const __bf16* qrb = qrg + (size_t)bh * L * DH;
    const __bf16* kb  = kg  + (size_t)bh * L * DH;
    const __bf16* vb  = vg  + (size_t)bh * L * DH;
    const __bf16* rkb = rkg + (size_t)n  * L * DH;

    bf16x8 qwf[2], qrf[2];
    #pragma unroll
    for (int ks = 0; ks < 2; ++ks) {
        size_t off = (size_t)(i0w + row16) * DH + kgrp * 8 + ks * 32;
        qwf[ks] = *reinterpret_cast<const bf16x8*>(qwb + off);
        qrf[ks] = *reinterpret_cast<const bf16x8*>(qrb + off);
    }

    float m_run[4], l_run[4];
    f32x4 O[4];
    #pragma unroll
    for (int r = 0; r < 4; ++r) { m_run[r] = -INFINITY; l_run[r] = 0.f; }
    #pragma unroll
    for (int cb = 0; cb < 4; ++cb) O[cb] = (f32x4){0.f, 0.f, 0.f, 0.f};

    for (int j0 = 0; j0 <= i0 + 63; j0 += 64) {
        __syncthreads();

        {
            int j  = t >> 2;
            int d0 = (t & 3) * 16;
            bf16x8 ka = *reinterpret_cast<const bf16x8*>(kb + (size_t)(j0 + j) * DH + d0);
            bf16x8 kb2 = *reinterpret_cast<const bf16x8*>(kb + (size_t)(j0 + j) * DH + d0 + 8);
            *reinterpret_cast<bf16x8*>(&kt[j][d0])     = ka;
            *reinterpret_cast<bf16x8*>(&kt[j][d0 + 8]) = kb2;
            bf16x8 va = *reinterpret_cast<const bf16x8*>(vb + (size_t)(j0 + j) * DH + d0);
            bf16x8 vb2 = *reinterpret_cast<const bf16x8*>(vb + (size_t)(j0 + j) * DH + d0 + 8);
            #pragma unroll
            for (int kk = 0; kk < 8; ++kk) {
                vtT[d0 + kk][j]     = va[kk];
                vtT[d0 + 8 + kk][j] = vb2[kk];
            }
        }
        {
            const int p0 = (L - 1) + j0 - (i0 + 63);
            for (int l = t; l < 128 * 4; l += 256) {
                int rr = l >> 2;
                int d0 = (l & 3) * 16;
                int p  = p0 + rr; if (p > L - 1) p = L - 1;
                bf16x8 ra = *reinterpret_cast<const bf16x8*>(rkb + (size_t)p * DH + d0);
                bf16x8 rb2 = *reinterpret_cast<const bf16x8*>(rkb + (size_t)p * DH + d0 + 8);
                *reinterpret_cast<bf16x8*>(&rkt[rr][d0])     = ra;
                *reinterpret_cast<bf16x8*>(&rkt[rr][d0 + 8]) = rb2;
            }
        }
        __syncthreads();

        f32x4 ac[4];
        #pragma unroll
        for (int cb = 0; cb < 4; ++cb) ac[cb] = (f32x4){0.f, 0.f, 0.f, 0.f};
        #pragma unroll
        for (int ks = 0; ks < 2; ++ks)
            #pragma unroll
            for (int cb = 0; cb < 4; ++cb) {
                bf16x8 kf = *reinterpret_cast<const bf16x8*>(&kt[16 * cb + row16][kgrp * 8 + ks * 32]);
                ac[cb] = __builtin_amdgcn_mfma_f32_16x16x32_bf16(qwf[ks], kf, ac[cb], 0, 0, 0);
            }

        {
            f32x4 db[5];
            #pragma unroll
            for (int cb = 0; cb < 5; ++cb) db[cb] = (f32x4){0.f, 0.f, 0.f, 0.f};
            const int bandoff = 48 - 16 * w;
            #pragma unroll
            for (int ks = 0; ks < 2; ++ks)
                #pragma unroll
                for (int cb = 0; cb < 5; ++cb) {
                    bf16x8 rf = *reinterpret_cast<const bf16x8*>(&rkt[bandoff + 16 * cb + row16][kgrp * 8 + ks * 32]);
                    db[cb] = __builtin_amdgcn_mfma_f32_16x16x32_bf16(qrf[ks], rf, db[cb], 0, 0, 0);
                }
            #pragma unroll
            for (int cb = 0; cb < 5; ++cb)
                #pragma unroll
                for (int r = 0; r < 4; ++r)
                    dband[w][kgrp * 4 + r][16 * cb + row16] = db[cb][r];
        }

        #pragma unroll
        for (int r = 0; r < 4; ++r) {
            const int ri = kgrp * 4 + r;
            const int i_glob = i0w + ri;
            float sv[4];
            float rmax = -INFINITY;
            #pragma unroll
            for (int cb = 0; cb < 4; ++cb) {
                int jj = 16 * cb + row16;
                float s = SCALE_F * (ac[cb][r] + dband[w][ri][jj + 15 - ri]);
                if (j0 + jj > i_glob) s = -INFINITY;
                sv[cb] = s;
                rmax = fmaxf(rmax, s);
            }
            #pragma unroll
            for (int off = 1; off < 16; off <<= 1)
                rmax = fmaxf(rmax, __shfl_xor(rmax, off));
            float newm = fmaxf(m_run[r], rmax);
            float sc = expf(m_run[r] - newm);
            float rsum = 0.f;
            #pragma unroll
            for (int cb = 0; cb < 4; ++cb) {
                float p = expf(sv[cb] - newm);
                pt[w][ri][16 * cb + row16] = (__bf16)p;
                rsum += p;
            }
            #pragma unroll
            for (int off = 1; off < 16; off <<= 1)
                rsum += __shfl_xor(rsum, off);
            l_run[r] = l_run[r] * sc + rsum;
            m_run[r] = newm;
            #pragma unroll
            for (int cb = 0; cb < 4; ++cb) O[cb][r] *= sc;
        }

        #pragma unroll
        for (int ks = 0; ks < 2; ++ks) {
            bf16x8 pf = *reinterpret_cast<const bf16x8*>(&pt[w][row16][kgrp * 8 + ks * 32]);
            #pragma unroll
            for (int cb = 0; cb < 4; ++cb) {
                bf16x8 vf = *reinterpret_cast<const bf16x8*>(&vtT[16 * cb + row16][kgrp * 8 + ks * 32]);
                O[cb] = __builtin_amdgcn_mfma_f32_16x16x32_bf16(pf, vf, O[cb], 0, 0, 0);
            }
        }
    }

    #pragma unroll
    for (int r = 0; r < 4; ++r) {
        const int i_glob = i0w + kgrp * 4 + r;
        const float inv = 1.0f / l_run[r];
        #pragma unroll
        for (int cb = 0; cb < 4; ++cb) {
            av_out[(size_t)(i_glob * BSZ + b) * (NH * DH) + n * DH + 16 * cb + row16] =
                (__bf16)(O[cb][r] * inv);
        }
    }
}

// ---------------------------------------------------------------------------
// Fused residual + LayerNorm
// ---------------------------------------------------------------------------
__global__ __launch_bounds__(256)
void ln_fused(const float* __restrict__ w, const float* __restrict__ ao,
              const float* __restrict__ g, const float* __restrict__ bb,
              float* __restrict__ out)
{
    const int row = blockIdx.x;
    const float* wr = w  + (size_t)row * DM;
    const float* ar = ao + (size_t)row * DM;
    const int t = threadIdx.x;
    float x[4];
    float s = 0.f;
    #pragma unroll
    for (int j = 0; j < 4; ++j) {
        int c = t + j * 256;
        x[j] = wr[c] + ar[c];
        s += x[j];
    }
    __shared__ float red[4];
    #pragma unroll
    for (int off = 1; off < 64; off <<= 1) s += __shfl_xor(s, off);
    int wid = t >> 6, lane = t & 63;
    if (lane == 0) red[wid] = s;
    __syncthreads();
    float mu = (red[0] + red[1] + red[2] + red[3]) * (1.0f / DM);
    float ss = 0.f;
    #pragma unroll
    for (int j = 0; j < 4; ++j) { float d = x[j] - mu; ss += d * d; }
    #pragma unroll
    for (int off = 1; off < 64; off <<= 1) ss += __shfl_xor(ss, off);
    __syncthreads();
    if (lane == 0) red[wid] = ss;
    __syncthreads();
    float var = (red[0] + red[1] + red[2] + red[3]) * (1.0f / DM);
    float rstd = rsqrtf(var + 1e-5f);
    #pragma unroll
    for (int j = 0; j < 4; ++j) {
        int c = t + j * 256;
        out[(size_t)row * DM + c] = (x[j] - mu) * rstd * g[c] + bb[c];
    }
}

extern "C" void kernel_launch(void* const* d_in, const int* in_sizes, int n_in,
                              void* d_out, int out_size, void* d_ws, size_t ws_size,
                              hipStream_t stream)
{
    (void)in_sizes; (void)n_in; (void)out_size; (void)ws_size;
    const float* w   = (const float*)d_in[0];
    const float* r   = (const float*)d_in[1];
    const float* rwb = (const float*)d_in[2];
    const float* rrb = (const float*)d_in[3];
    const float* Wq  = (const float*)d_in[4];
    const float* bq  = (const float*)d_in[5];
    const float* Wk  = (const float*)d_in[6];
    const float* bk  = (const float*)d_in[7];
    const float* Wv  = (const float*)d_in[8];
    const float* bv  = (const float*)d_in[9];
    const float* Wr  = (const float*)d_in[10];
    const float* br  = (const float*)d_in[11];
    const float* Wo  = (const float*)d_in[12];
    const float* bo  = (const float*)d_in[13];
    const float* lng = (const float*)d_in[14];
    const float* lnb = (const float*)d_in[15];
    float* out = (float*)d_out;

    const size_t NQ = (size_t)BSZ * NH * L * DH;   // 4.19M
    char* wsb = (char*)d_ws;
    __bf16* w_bf    = (__bf16*)wsb;  wsb += (size_t)2 * L * DM * 2;       // [4096][1024]
    __bf16* r_bf    = (__bf16*)wsb;  wsb += (size_t)L * DM * 2;           // [2048][1024]
    __bf16* wqkv_t  = (__bf16*)wsb;  wsb += (size_t)3 * DM * DM * 2;      // [3072][1024]
    __bf16* wr_t    = (__bf16*)wsb;  wsb += (size_t)DM * DM * 2;
    __bf16* wo_t    = (__bf16*)wsb;  wsb += (size_t)DM * DM * 2;
    __bf16* qw_ws   = (__bf16*)wsb;  wsb += NQ * 2;
    __bf16* qr_ws   = (__bf16*)wsb;  wsb += NQ * 2;
    __bf16* k_ws    = (__bf16*)wsb;  wsb += NQ * 2;
    __bf16* v_ws    = (__bf16*)wsb;  wsb += NQ * 2;
    __bf16* rk_ws   = (__bf16*)wsb;  wsb += (size_t)NH * L * DH * 2;
    __bf16* av_ws   = (__bf16*)wsb;  wsb += NQ * 2;
    float*  ao_ws   = (float*)wsb;                                         // + NQ*4

    dim3 blk(256);
    // prep: casts + weight transposes
    cast_f32_bf16<<<dim3(1024), blk, 0, stream>>>(w, w_bf, (2 * L * DM) / 4);
    cast_f32_bf16<<<dim3(512),  blk, 0, stream>>>(r, r_bf, (L * DM) / 4);
    transpose_w5<<<dim3(32, 32, 5), blk, 0, stream>>>(
        Wq, Wk, Wv, Wr, Wo,
        wqkv_t, wqkv_t + (size_t)DM * DM, wqkv_t + (size_t)2 * DM * DM, wr_t, wo_t);

    // fused QKV projection: [4096x1024] @ [1024x3072]
    gemm_bf16<<<dim3(32, 24), blk, 0, stream>>>(w_bf, wqkv_t, 0,
        qw_ws, qr_ws, k_ws, v_ws, bq, bk, bv, rwb, rrb, nullptr);
    // r projection: [2048x1024] @ [1024x1024]
    gemm_bf16<<<dim3(16, 8), blk, 0, stream>>>(r_bf, wr_t, 1,
        rk_ws, nullptr, nullptr, nullptr, br, nullptr, nullptr, nullptr, nullptr, nullptr);

    attn_mfma<<<dim3(L / 64, BSZ * NH), blk, 0, stream>>>(qw_ws, qr_ws, k_ws, v_ws, rk_ws, av_ws);

    // output projection: [4096x1024] @ [1024x1024] -> fp32
    gemm_bf16<<<dim3(32, 8), blk, 0, stream>>>(av_ws, wo_t, 2,
        nullptr, nullptr, nullptr, nullptr, bo, nullptr, nullptr, nullptr, nullptr, ao_ws);

    ln_fused<<<dim3(L * BSZ), blk, 0, stream>>>(w, ao_ws, lng, lnb, out);
}

// Round 7
// 508.661 us; speedup vs baseline: 5.5149x; 1.0269x over previous
//
#include <hip/hip_runtime.h>
#include <math.h>

#define L 2048
#define BSZ 2
#define NH 16
#define DH 64
#define DM 1024
#define GK 1024
#define SCALE_F 0.125f

typedef __attribute__((ext_vector_type(8))) __bf16 bf16x8;
typedef __attribute__((ext_vector_type(4))) __bf16 bf16x4;
typedef __attribute__((ext_vector_type(4))) float f32x4;

// ---------------------------------------------------------------------------
// cast fp32 -> bf16 for two tensors in one launch
// ---------------------------------------------------------------------------
__global__ __launch_bounds__(256)
void cast2_f32_bf16(const float* __restrict__ a, int na4,
                    const float* __restrict__ b, int nb4,
                    __bf16* __restrict__ da, __bf16* __restrict__ db_)
{
    int i = blockIdx.x * 256 + threadIdx.x;
    int stride = gridDim.x * 256;
    int tot = na4 + nb4;
    for (; i < tot; i += stride) {
        const float4* s; bf16x4* d; int idx;
        if (i < na4) { s = (const float4*)a; d = (bf16x4*)da; idx = i; }
        else         { s = (const float4*)b; d = (bf16x4*)db_; idx = i - na4; }
        float4 v = s[idx];
        bf16x4 o = { (__bf16)v.x, (__bf16)v.y, (__bf16)v.z, (__bf16)v.w };
        d[idx] = o;
    }
}

// ---------------------------------------------------------------------------
// Transpose 5x [1024x1024] fp32 -> bf16 transposed
// ---------------------------------------------------------------------------
__global__ __launch_bounds__(256)
void transpose_w5(const float* s0, const float* s1, const float* s2,
                  const float* s3, const float* s4,
                  __bf16* d0, __bf16* d1, __bf16* d2, __bf16* d3, __bf16* d4)
{
    const float* srcs[5] = { s0, s1, s2, s3, s4 };
    __bf16*      dsts[5] = { d0, d1, d2, d3, d4 };
    const float* src = srcs[blockIdx.z];
    __bf16*      dst = dsts[blockIdx.z];
    __shared__ float tile[32][33];
    const int tx = threadIdx.x & 31, ty = threadIdx.x >> 5;
    const int x0 = blockIdx.x * 32, y0 = blockIdx.y * 32;
    #pragma unroll
    for (int i = 0; i < 32; i += 8)
        tile[ty + i][tx] = src[(size_t)(y0 + ty + i) * 1024 + x0 + tx];
    __syncthreads();
    #pragma unroll
    for (int i = 0; i < 32; i += 8)
        dst[(size_t)(x0 + ty + i) * 1024 + y0 + tx] = (__bf16)tile[tx][ty + i];
}

// ---------------------------------------------------------------------------
// bf16 MFMA GEMM, m97 structure. sched 0: flattened QKV(768 blocks)+RK(128,
// writes o4 with bias b3). sched 1: O-projection (2D grid), fp32 out.
// ---------------------------------------------------------------------------
__global__ __launch_bounds__(256)
void gemm_bf16(const __bf16* __restrict__ A0, const __bf16* __restrict__ A1,
               const __bf16* __restrict__ B0, const __bf16* __restrict__ B1,
               int sched,
               __bf16* __restrict__ o0, __bf16* __restrict__ o1,
               __bf16* __restrict__ o2, __bf16* __restrict__ o3,
               __bf16* __restrict__ o4,
               const float* __restrict__ b0, const float* __restrict__ b1,
               const float* __restrict__ b2, const float* __restrict__ b3,
               const float* __restrict__ rwbf, const float* __restrict__ rrbf,
               float* __restrict__ of)
{
    __shared__ __bf16 As[128 * 64];
    __shared__ __bf16 Bs[128 * 64];

    const __bf16 *A, *Bt;
    int mode, bm, bn;
    if (sched == 0) {
        int id = blockIdx.x;
        if (id < 768) { A = A0; Bt = B0; mode = 0; bm = (id & 31) * 128; bn = (id >> 5) * 128; }
        else { id -= 768; A = A1; Bt = B1; mode = 1; bm = (id & 15) * 128; bn = (id >> 4) * 128; }
    } else {
        A = A0; Bt = B0; mode = 2; bm = blockIdx.x * 128; bn = blockIdx.y * 128;
    }

    const int t    = threadIdx.x;
    const int w    = t >> 6;
    const int lane = t & 63;
    const int row16 = lane & 15;
    const int kgrp  = lane >> 4;
    const int wr = w >> 1, wc = w & 1;

    f32x4 acc[4][4];
    #pragma unroll
    for (int mi = 0; mi < 4; ++mi)
        #pragma unroll
        for (int ni = 0; ni < 4; ++ni)
            acc[mi][ni] = (f32x4){0.f, 0.f, 0.f, 0.f};

    for (int k0 = 0; k0 < GK; k0 += 64) {
        __syncthreads();
        #pragma unroll
        for (int it = 0; it < 4; ++it) {
            const int lin = (it * 256 + t) * 16;
            const int row = lin >> 7;
            const int kb  = lin & 127;
            const char* ga = (const char*)(A + (size_t)(bm + row) * GK + k0) + kb;
            __builtin_amdgcn_global_load_lds(
                (const __attribute__((address_space(1))) void*)ga,
                (__attribute__((address_space(3))) void*)((char*)As + lin), 16, 0, 0);
            const char* gb = (const char*)(Bt + (size_t)(bn + row) * GK + k0) + kb;
            __builtin_amdgcn_global_load_lds(
                (const __attribute__((address_space(1))) void*)gb,
                (__attribute__((address_space(3))) void*)((char*)Bs + lin), 16, 0, 0);
        }
        __syncthreads();

        #pragma unroll
        for (int ks = 0; ks < 2; ++ks) {
            bf16x8 af[4], bfr[4];
            #pragma unroll
            for (int mi = 0; mi < 4; ++mi)
                af[mi] = *reinterpret_cast<const bf16x8*>(
                    &As[(wr * 64 + mi * 16 + row16) * 64 + kgrp * 8 + ks * 32]);
            #pragma unroll
            for (int ni = 0; ni < 4; ++ni)
                bfr[ni] = *reinterpret_cast<const bf16x8*>(
                    &Bs[(wc * 64 + ni * 16 + row16) * 64 + kgrp * 8 + ks * 32]);
            #pragma unroll
            for (int mi = 0; mi < 4; ++mi)
                #pragma unroll
                for (int ni = 0; ni < 4; ++ni)
                    acc[mi][ni] = __builtin_amdgcn_mfma_f32_16x16x32_bf16(
                        af[mi], bfr[ni], acc[mi][ni], 0, 0, 0);
        }
    }

    #pragma unroll
    for (int mi = 0; mi < 4; ++mi) {
        #pragma unroll
        for (int ni = 0; ni < 4; ++ni) {
            #pragma unroll
            for (int r = 0; r < 4; ++r) {
                const int row = bm + wr * 64 + mi * 16 + kgrp * 4 + r;
                const int col = bn + wc * 64 + ni * 16 + row16;
                const float val = acc[mi][ni][r];
                if (mode == 0) {
                    const int which = col >> 10, c = col & 1023;
                    const int n = c >> 6, dh = c & 63;
                    const int i = row >> 1, b = row & 1;
                    const size_t idx = (((size_t)(b * NH + n) * L) + i) * DH + dh;
                    if (which == 0) {
                        const float v0 = val + b0[c];
                        o0[idx] = (__bf16)(v0 + rwbf[c]);
                        o1[idx] = (__bf16)(v0 + rrbf[c]);
                    } else if (which == 1) {
                        o2[idx] = (__bf16)(val + b1[c]);
                    } else {
                        o3[idx] = (__bf16)(val + b2[c]);
                    }
                } else if (mode == 1) {
                    const int n = col >> 6, dh = col & 63;
                    o4[((size_t)n * L + row) * DH + dh] = (__bf16)(val + b3[col]);
                } else {
                    of[(size_t)row * DM + col] = val + b0[col];
                }
            }
        }
    }
}

// ---------------------------------------------------------------------------
// MFMA flash attention, TXL rel-shift via in-register shuffle.
// LDS: kt + vtT + pt = 27.6 KB -> 4 blocks/CU. Fixed m=0 softmax (scores
// bounded by design), BD B-frags direct from global (L2-resident rk).
// ---------------------------------------------------------------------------
__global__ __launch_bounds__(256, 4)
void attn_mfma(const __bf16* __restrict__ qwg, const __bf16* __restrict__ qrg,
               const __bf16* __restrict__ kg,  const __bf16* __restrict__ vg,
               const __bf16* __restrict__ rkg, __bf16* __restrict__ av_out)
{
    __shared__ __bf16 kt [64][72];
    __shared__ __bf16 vtT[64][72];     // transposed V: vtT[d][j]
    __shared__ __bf16 pt [4][16][72];  // per-wave P tile

    const int t    = threadIdx.x;
    const int w    = t >> 6;
    const int lane = t & 63;
    const int row16 = lane & 15;
    const int kgrp  = lane >> 4;

    const int bh = blockIdx.y;
    const int n  = bh & (NH - 1);
    const int b  = bh >> 4;
    const int i0 = (gridDim.x - 1 - blockIdx.x) * 64;   // long blocks first
    const int i0w = i0 + w * 16;

    const __bf16* qwb = qwg + (size_t)bh * L * DH;
    const __bf16* qrb = qrg + (size_t)bh * L * DH;
    const __bf16* kb  = kg  + (size_t)bh * L * DH;
    const __bf16* vb  = vg  + (size_t)bh * L * DH;
    const __bf16* rkb = rkg + (size_t)n  * L * DH;

    bf16x8 qwf[2], qrf[2];
    #pragma unroll
    for (int ks = 0; ks < 2; ++ks) {
        size_t off = (size_t)(i0w + row16) * DH + kgrp * 8 + ks * 32;
        qwf[ks] = *reinterpret_cast<const bf16x8*>(qwb + off);
        qrf[ks] = *reinterpret_cast<const bf16x8*>(qrb + off);
    }

    float l_run[4] = {0.f, 0.f, 0.f, 0.f};
    f32x4 O[4];
    #pragma unroll
    for (int cb = 0; cb < 4; ++cb) O[cb] = (f32x4){0.f, 0.f, 0.f, 0.f};

    for (int j0 = 0; j0 <= i0 + 63; j0 += 64) {
        __syncthreads();   // kt/vtT safe to overwrite

        // ---- stage K tile + transposed V tile ----
        {
            int j  = t >> 2;
            int d0 = (t & 3) * 16;
            bf16x8 ka  = *reinterpret_cast<const bf16x8*>(kb + (size_t)(j0 + j) * DH + d0);
            bf16x8 kb2 = *reinterpret_cast<const bf16x8*>(kb + (size_t)(j0 + j) * DH + d0 + 8);
            *reinterpret_cast<bf16x8*>(&kt[j][d0])     = ka;
            *reinterpret_cast<bf16x8*>(&kt[j][d0 + 8]) = kb2;
            bf16x8 va  = *reinterpret_cast<const bf16x8*>(vb + (size_t)(j0 + j) * DH + d0);
            bf16x8 vb2 = *reinterpret_cast<const bf16x8*>(vb + (size_t)(j0 + j) * DH + d0 + 8);
            #pragma unroll
            for (int kk = 0; kk < 8; ++kk) {
                vtT[d0 + kk][j]     = va[kk];
                vtT[d0 + 8 + kk][j] = vb2[kk];
            }
        }
        __syncthreads();

        // ---- AC = QW · K^T ----
        f32x4 ac[4];
        #pragma unroll
        for (int cb = 0; cb < 4; ++cb) ac[cb] = (f32x4){0.f, 0.f, 0.f, 0.f};
        #pragma unroll
        for (int ks = 0; ks < 2; ++ks)
            #pragma unroll
            for (int cb = 0; cb < 4; ++cb) {
                bf16x8 kf = *reinterpret_cast<const bf16x8*>(&kt[16 * cb + row16][kgrp * 8 + ks * 32]);
                ac[cb] = __builtin_amdgcn_mfma_f32_16x16x32_bf16(qwf[ks], kf, ac[cb], 0, 0, 0);
            }

        // ---- Dband = QR · RK_band^T, B-frags direct from global ----
        f32x4 db[5];
        #pragma unroll
        for (int cb = 0; cb < 5; ++cb) db[cb] = (f32x4){0.f, 0.f, 0.f, 0.f};
        const int pw0 = (L - 1) + j0 - (i0w + 15);
        #pragma unroll
        for (int ks = 0; ks < 2; ++ks)
            #pragma unroll
            for (int cb = 0; cb < 5; ++cb) {
                int p = pw0 + 16 * cb + row16;
                p = p > (L - 1) ? (L - 1) : p;     // clamped rows feed masked cols only
                bf16x8 rf = *reinterpret_cast<const bf16x8*>(
                    rkb + (size_t)p * DH + kgrp * 8 + ks * 32);
                db[cb] = __builtin_amdgcn_mfma_f32_16x16x32_bf16(qrf[ks], rf, db[cb], 0, 0, 0);
            }

        // ---- softmax (fixed m=0) with in-register shift ----
        #pragma unroll
        for (int r = 0; r < 4; ++r) {
            const int ri = kgrp * 4 + r;
            const int i_glob = i0w + ri;
            const int u  = row16 + 15 - ri;        // 0..30
            const int lo = u & 15;
            const int hi = u >> 4;
            const int srclane = (lane & 48) | lo;
            float T[5];
            #pragma unroll
            for (int c2 = 0; c2 < 5; ++c2)
                T[c2] = __shfl(db[c2][r], srclane, 64);
            float rsum = 0.f;
            #pragma unroll
            for (int cb = 0; cb < 4; ++cb) {
                const int jj = 16 * cb + row16;
                float bd = hi ? T[cb + 1] : T[cb];
                float s = SCALE_F * (ac[cb][r] + bd);
                if (j0 + jj > i_glob) s = -INFINITY;
                float p = __expf(s);
                pt[w][ri][jj] = (__bf16)p;
                rsum += p;
            }
            #pragma unroll
            for (int off = 1; off < 16; off <<= 1)
                rsum += __shfl_xor(rsum, off);
            l_run[r] += rsum;
        }

        // ---- O += P · V ----
        #pragma unroll
        for (int ks = 0; ks < 2; ++ks) {
            bf16x8 pf = *reinterpret_cast<const bf16x8*>(&pt[w][row16][kgrp * 8 + ks * 32]);
            #pragma unroll
            for (int cb = 0; cb < 4; ++cb) {
                bf16x8 vf = *reinterpret_cast<const bf16x8*>(&vtT[16 * cb + row16][kgrp * 8 + ks * 32]);
                O[cb] = __builtin_amdgcn_mfma_f32_16x16x32_bf16(pf, vf, O[cb], 0, 0, 0);
            }
        }
    }

    #pragma unroll
    for (int r = 0; r < 4; ++r) {
        const int i_glob = i0w + kgrp * 4 + r;
        const float inv = 1.0f / l_run[r];
        #pragma unroll
        for (int cb = 0; cb < 4; ++cb) {
            av_out[(size_t)(i_glob * BSZ + b) * (NH * DH) + n * DH + 16 * cb + row16] =
                (__bf16)(O[cb][r] * inv);
        }
    }
}

// ---------------------------------------------------------------------------
// Fused residual + LayerNorm
// ---------------------------------------------------------------------------
__global__ __launch_bounds__(256)
void ln_fused(const float* __restrict__ w, const float* __restrict__ ao,
              const float* __restrict__ g, const float* __restrict__ bb,
              float* __restrict__ out)
{
    const int row = blockIdx.x;
    const float* wr = w  + (size_t)row * DM;
    const float* ar = ao + (size_t)row * DM;
    const int t = threadIdx.x;
    float x[4];
    float s = 0.f;
    #pragma unroll
    for (int j = 0; j < 4; ++j) {
        int c = t + j * 256;
        x[j] = wr[c] + ar[c];
        s += x[j];
    }
    __shared__ float red[4];
    #pragma unroll
    for (int off = 1; off < 64; off <<= 1) s += __shfl_xor(s, off);
    int wid = t >> 6, lane = t & 63;
    if (lane == 0) red[wid] = s;
    __syncthreads();
    float mu = (red[0] + red[1] + red[2] + red[3]) * (1.0f / DM);
    float ss = 0.f;
    #pragma unroll
    for (int j = 0; j < 4; ++j) { float d = x[j] - mu; ss += d * d; }
    #pragma unroll
    for (int off = 1; off < 64; off <<= 1) ss += __shfl_xor(ss, off);
    __syncthreads();
    if (lane == 0) red[wid] = ss;
    __syncthreads();
    float var = (red[0] + red[1] + red[2] + red[3]) * (1.0f / DM);
    float rstd = rsqrtf(var + 1e-5f);
    #pragma unroll
    for (int j = 0; j < 4; ++j) {
        int c = t + j * 256;
        out[(size_t)row * DM + c] = (x[j] - mu) * rstd * g[c] + bb[c];
    }
}

extern "C" void kernel_launch(void* const* d_in, const int* in_sizes, int n_in,
                              void* d_out, int out_size, void* d_ws, size_t ws_size,
                              hipStream_t stream)
{
    (void)in_sizes; (void)n_in; (void)out_size; (void)ws_size;
    const float* w   = (const float*)d_in[0];
    const float* r   = (const float*)d_in[1];
    const float* rwb = (const float*)d_in[2];
    const float* rrb = (const float*)d_in[3];
    const float* Wq  = (const float*)d_in[4];
    const float* bq  = (const float*)d_in[5];
    const float* Wk  = (const float*)d_in[6];
    const float* bk  = (const float*)d_in[7];
    const float* Wv  = (const float*)d_in[8];
    const float* bv  = (const float*)d_in[9];
    const float* Wr  = (const float*)d_in[10];
    const float* br  = (const float*)d_in[11];
    const float* Wo  = (const float*)d_in[12];
    const float* bo  = (const float*)d_in[13];
    const float* lng = (const float*)d_in[14];
    const float* lnb = (const float*)d_in[15];
    float* out = (float*)d_out;

    const size_t NQ = (size_t)BSZ * NH * L * DH;   // 4.19M
    char* wsb = (char*)d_ws;
    __bf16* w_bf    = (__bf16*)wsb;  wsb += (size_t)2 * L * DM * 2;
    __bf16* r_bf    = (__bf16*)wsb;  wsb += (size_t)L * DM * 2;
    __bf16* wqkv_t  = (__bf16*)wsb;  wsb += (size_t)3 * DM * DM * 2;
    __bf16* wr_t    = (__bf16*)wsb;  wsb += (size_t)DM * DM * 2;
    __bf16* wo_t    = (__bf16*)wsb;  wsb += (size_t)DM * DM * 2;
    __bf16* qw_ws   = (__bf16*)wsb;  wsb += NQ * 2;
    __bf16* qr_ws   = (__bf16*)wsb;  wsb += NQ * 2;
    __bf16* k_ws    = (__bf16*)wsb;  wsb += NQ * 2;
    __bf16* v_ws    = (__bf16*)wsb;  wsb += NQ * 2;
    __bf16* rk_ws   = (__bf16*)wsb;  wsb += (size_t)NH * L * DH * 2;
    __bf16* av_ws   = (__bf16*)wsb;  wsb += NQ * 2;
    float*  ao_ws   = (float*)wsb;

    dim3 blk(256);
    cast2_f32_bf16<<<dim3(1536), blk, 0, stream>>>(
        w, (2 * L * DM) / 4, r, (L * DM) / 4, w_bf, r_bf);
    transpose_w5<<<dim3(32, 32, 5), blk, 0, stream>>>(
        Wq, Wk, Wv, Wr, Wo,
        wqkv_t, wqkv_t + (size_t)DM * DM, wqkv_t + (size_t)2 * DM * DM, wr_t, wo_t);

    // fused QKV (768 blocks) + RK (128 blocks -> o4/b3)
    gemm_bf16<<<dim3(896), blk, 0, stream>>>(w_bf, r_bf, wqkv_t, wr_t, 0,
        qw_ws, qr_ws, k_ws, v_ws, rk_ws, bq, bk, bv, br, rwb, rrb, nullptr);

    attn_mfma<<<dim3(L / 64, BSZ * NH), blk, 0, stream>>>(qw_ws, qr_ws, k_ws, v_ws, rk_ws, av_ws);

    // output projection -> fp32
    gemm_bf16<<<dim3(32, 8), blk, 0, stream>>>(av_ws, nullptr, wo_t, nullptr, 1,
        nullptr, nullptr, nullptr, nullptr, nullptr, bo, nullptr, nullptr, nullptr,
        nullptr, nullptr, ao_ws);

    ln_fused<<<dim3(L * BSZ), blk, 0, stream>>>(w, ao_ws, lng, lnb, out);
}

// Round 8
// 421.416 us; speedup vs baseline: 6.6566x; 1.2070x over previous
//
#include <hip/hip_runtime.h>
#include <math.h>

#define L 2048
#define BSZ 2
#define NH 16
#define DH 64
#define DM 1024
#define GK 1024
#define SCALE_F 0.125f

// partial-accumulator slot: 64x64 O (f32) + 64 l values
#define PSLOT 4160

typedef __attribute__((ext_vector_type(8))) __bf16 bf16x8;
typedef __attribute__((ext_vector_type(4))) __bf16 bf16x4;
typedef __attribute__((ext_vector_type(4))) float f32x4;

// ---------------------------------------------------------------------------
// cast fp32 -> bf16 for two tensors in one launch
// ---------------------------------------------------------------------------
__global__ __launch_bounds__(256)
void cast2_f32_bf16(const float* __restrict__ a, int na4,
                    const float* __restrict__ b, int nb4,
                    __bf16* __restrict__ da, __bf16* __restrict__ db_)
{
    int i = blockIdx.x * 256 + threadIdx.x;
    int stride = gridDim.x * 256;
    int tot = na4 + nb4;
    for (; i < tot; i += stride) {
        const float4* s; bf16x4* d; int idx;
        if (i < na4) { s = (const float4*)a; d = (bf16x4*)da; idx = i; }
        else         { s = (const float4*)b; d = (bf16x4*)db_; idx = i - na4; }
        float4 v = s[idx];
        bf16x4 o = { (__bf16)v.x, (__bf16)v.y, (__bf16)v.z, (__bf16)v.w };
        d[idx] = o;
    }
}

// ---------------------------------------------------------------------------
// Transpose 5x [1024x1024] fp32 -> bf16 transposed
// ---------------------------------------------------------------------------
__global__ __launch_bounds__(256)
void transpose_w5(const float* s0, const float* s1, const float* s2,
                  const float* s3, const float* s4,
                  __bf16* d0, __bf16* d1, __bf16* d2, __bf16* d3, __bf16* d4)
{
    const float* srcs[5] = { s0, s1, s2, s3, s4 };
    __bf16*      dsts[5] = { d0, d1, d2, d3, d4 };
    const float* src = srcs[blockIdx.z];
    __bf16*      dst = dsts[blockIdx.z];
    __shared__ float tile[32][33];
    const int tx = threadIdx.x & 31, ty = threadIdx.x >> 5;
    const int x0 = blockIdx.x * 32, y0 = blockIdx.y * 32;
    #pragma unroll
    for (int i = 0; i < 32; i += 8)
        tile[ty + i][tx] = src[(size_t)(y0 + ty + i) * 1024 + x0 + tx];
    __syncthreads();
    #pragma unroll
    for (int i = 0; i < 32; i += 8)
        dst[(size_t)(x0 + ty + i) * 1024 + y0 + tx] = (__bf16)tile[tx][ty + i];
}

// ---------------------------------------------------------------------------
// bf16 MFMA GEMM, m97 structure. sched 0: flattened QKV(768 blocks)+RK(128,
// writes o4 with bias b3). sched 1: O-projection (2D grid), fp32 out.
// ---------------------------------------------------------------------------
__global__ __launch_bounds__(256)
void gemm_bf16(const __bf16* __restrict__ A0, const __bf16* __restrict__ A1,
               const __bf16* __restrict__ B0, const __bf16* __restrict__ B1,
               int sched,
               __bf16* __restrict__ o0, __bf16* __restrict__ o1,
               __bf16* __restrict__ o2, __bf16* __restrict__ o3,
               __bf16* __restrict__ o4,
               const float* __restrict__ b0, const float* __restrict__ b1,
               const float* __restrict__ b2, const float* __restrict__ b3,
               const float* __restrict__ rwbf, const float* __restrict__ rrbf,
               float* __restrict__ of)
{
    __shared__ __bf16 As[128 * 64];
    __shared__ __bf16 Bs[128 * 64];

    const __bf16 *A, *Bt;
    int mode, bm, bn;
    if (sched == 0) {
        int id = blockIdx.x;
        if (id < 768) { A = A0; Bt = B0; mode = 0; bm = (id & 31) * 128; bn = (id >> 5) * 128; }
        else { id -= 768; A = A1; Bt = B1; mode = 1; bm = (id & 15) * 128; bn = (id >> 4) * 128; }
    } else {
        A = A0; Bt = B0; mode = 2; bm = blockIdx.x * 128; bn = blockIdx.y * 128;
    }

    const int t    = threadIdx.x;
    const int w    = t >> 6;
    const int lane = t & 63;
    const int row16 = lane & 15;
    const int kgrp  = lane >> 4;
    const int wr = w >> 1, wc = w & 1;

    f32x4 acc[4][4];
    #pragma unroll
    for (int mi = 0; mi < 4; ++mi)
        #pragma unroll
        for (int ni = 0; ni < 4; ++ni)
            acc[mi][ni] = (f32x4){0.f, 0.f, 0.f, 0.f};

    for (int k0 = 0; k0 < GK; k0 += 64) {
        __syncthreads();
        #pragma unroll
        for (int it = 0; it < 4; ++it) {
            const int lin = (it * 256 + t) * 16;
            const int row = lin >> 7;
            const int kb  = lin & 127;
            const char* ga = (const char*)(A + (size_t)(bm + row) * GK + k0) + kb;
            __builtin_amdgcn_global_load_lds(
                (const __attribute__((address_space(1))) void*)ga,
                (__attribute__((address_space(3))) void*)((char*)As + lin), 16, 0, 0);
            const char* gb = (const char*)(Bt + (size_t)(bn + row) * GK + k0) + kb;
            __builtin_amdgcn_global_load_lds(
                (const __attribute__((address_space(1))) void*)gb,
                (__attribute__((address_space(3))) void*)((char*)Bs + lin), 16, 0, 0);
        }
        __syncthreads();

        #pragma unroll
        for (int ks = 0; ks < 2; ++ks) {
            bf16x8 af[4], bfr[4];
            #pragma unroll
            for (int mi = 0; mi < 4; ++mi)
                af[mi] = *reinterpret_cast<const bf16x8*>(
                    &As[(wr * 64 + mi * 16 + row16) * 64 + kgrp * 8 + ks * 32]);
            #pragma unroll
            for (int ni = 0; ni < 4; ++ni)
                bfr[ni] = *reinterpret_cast<const bf16x8*>(
                    &Bs[(wc * 64 + ni * 16 + row16) * 64 + kgrp * 8 + ks * 32]);
            #pragma unroll
            for (int mi = 0; mi < 4; ++mi)
                #pragma unroll
                for (int ni = 0; ni < 4; ++ni)
                    acc[mi][ni] = __builtin_amdgcn_mfma_f32_16x16x32_bf16(
                        af[mi], bfr[ni], acc[mi][ni], 0, 0, 0);
        }
    }

    #pragma unroll
    for (int mi = 0; mi < 4; ++mi) {
        #pragma unroll
        for (int ni = 0; ni < 4; ++ni) {
            #pragma unroll
            for (int r = 0; r < 4; ++r) {
                const int row = bm + wr * 64 + mi * 16 + kgrp * 4 + r;
                const int col = bn + wc * 64 + ni * 16 + row16;
                const float val = acc[mi][ni][r];
                if (mode == 0) {
                    const int which = col >> 10, c = col & 1023;
                    const int n = c >> 6, dh = c & 63;
                    const int i = row >> 1, b = row & 1;
                    const size_t idx = (((size_t)(b * NH + n) * L) + i) * DH + dh;
                    if (which == 0) {
                        const float v0 = val + b0[c];
                        o0[idx] = (__bf16)(v0 + rwbf[c]);
                        o1[idx] = (__bf16)(v0 + rrbf[c]);
                    } else if (which == 1) {
                        o2[idx] = (__bf16)(val + b1[c]);
                    } else {
                        o3[idx] = (__bf16)(val + b2[c]);
                    }
                } else if (mode == 1) {
                    const int n = col >> 6, dh = col & 63;
                    o4[((size_t)n * L + row) * DH + dh] = (__bf16)(val + b3[col]);
                } else {
                    of[(size_t)row * DM + col] = val + b0[col];
                }
            }
        }
    }
}

// ---------------------------------------------------------------------------
// Flash-decoding attention partials. Fixed m=0 softmax -> partials combine
// by pure ADDITION. Block = (bh, i-tile of 64 rows, j-chunk of <=512 cols).
// Grid x=80 encodes (it, jc): it/8+1 chunks per i-tile. AtomicAdd into P.
// ---------------------------------------------------------------------------
__global__ __launch_bounds__(256, 4)
void attn_partial(const __bf16* __restrict__ qwg, const __bf16* __restrict__ qrg,
                  const __bf16* __restrict__ kg,  const __bf16* __restrict__ vg,
                  const __bf16* __restrict__ rkg, float* __restrict__ P)
{
    __shared__ __bf16 kt [64][72];
    __shared__ __bf16 vtT[64][72];     // transposed V: vtT[d][j]
    __shared__ __bf16 pt [4][16][72];  // per-wave P tile

    // decode chunk id
    int x = blockIdx.x;
    int it, jc;
    if (x < 8)       { it = x;                      jc = 0; }
    else if (x < 24) { int y = x - 8;  it = 8  + (y >> 1); jc = y & 1; }
    else if (x < 48) { int y = x - 24; it = 16 + y / 3;    jc = y - (y / 3) * 3; }
    else             { int y = x - 48; it = 24 + (y >> 2); jc = y & 3; }

    const int t    = threadIdx.x;
    const int w    = t >> 6;
    const int lane = t & 63;
    const int row16 = lane & 15;
    const int kgrp  = lane >> 4;

    const int bh = blockIdx.y;
    const int n  = bh & (NH - 1);
    const int i0 = it * 64;
    const int i0w = i0 + w * 16;
    const int jstart = jc * 512;
    const int jend   = min(jstart + 512, i0 + 64);   // exclusive

    const __bf16* qwb = qwg + (size_t)bh * L * DH;
    const __bf16* qrb = qrg + (size_t)bh * L * DH;
    const __bf16* kb  = kg  + (size_t)bh * L * DH;
    const __bf16* vb  = vg  + (size_t)bh * L * DH;
    const __bf16* rkb = rkg + (size_t)n  * L * DH;

    bf16x8 qwf[2], qrf[2];
    #pragma unroll
    for (int ks = 0; ks < 2; ++ks) {
        size_t off = (size_t)(i0w + row16) * DH + kgrp * 8 + ks * 32;
        qwf[ks] = *reinterpret_cast<const bf16x8*>(qwb + off);
        qrf[ks] = *reinterpret_cast<const bf16x8*>(qrb + off);
    }

    float l_run[4] = {0.f, 0.f, 0.f, 0.f};
    f32x4 O[4];
    #pragma unroll
    for (int cb = 0; cb < 4; ++cb) O[cb] = (f32x4){0.f, 0.f, 0.f, 0.f};

    for (int j0 = jstart; j0 < jend; j0 += 64) {
        __syncthreads();   // kt/vtT safe to overwrite

        // ---- stage K tile + transposed V tile ----
        {
            int j  = t >> 2;
            int d0 = (t & 3) * 16;
            bf16x8 ka  = *reinterpret_cast<const bf16x8*>(kb + (size_t)(j0 + j) * DH + d0);
            bf16x8 kb2 = *reinterpret_cast<const bf16x8*>(kb + (size_t)(j0 + j) * DH + d0 + 8);
            *reinterpret_cast<bf16x8*>(&kt[j][d0])     = ka;
            *reinterpret_cast<bf16x8*>(&kt[j][d0 + 8]) = kb2;
            bf16x8 va  = *reinterpret_cast<const bf16x8*>(vb + (size_t)(j0 + j) * DH + d0);
            bf16x8 vb2 = *reinterpret_cast<const bf16x8*>(vb + (size_t)(j0 + j) * DH + d0 + 8);
            #pragma unroll
            for (int kk = 0; kk < 8; ++kk) {
                vtT[d0 + kk][j]     = va[kk];
                vtT[d0 + 8 + kk][j] = vb2[kk];
            }
        }
        __syncthreads();

        // ---- AC = QW · K^T ----
        f32x4 ac[4];
        #pragma unroll
        for (int cb = 0; cb < 4; ++cb) ac[cb] = (f32x4){0.f, 0.f, 0.f, 0.f};
        #pragma unroll
        for (int ks = 0; ks < 2; ++ks)
            #pragma unroll
            for (int cb = 0; cb < 4; ++cb) {
                bf16x8 kf = *reinterpret_cast<const bf16x8*>(&kt[16 * cb + row16][kgrp * 8 + ks * 32]);
                ac[cb] = __builtin_amdgcn_mfma_f32_16x16x32_bf16(qwf[ks], kf, ac[cb], 0, 0, 0);
            }

        // ---- Dband = QR · RK_band^T, B-frags direct from global ----
        f32x4 db[5];
        #pragma unroll
        for (int cb = 0; cb < 5; ++cb) db[cb] = (f32x4){0.f, 0.f, 0.f, 0.f};
        const int pw0 = (L - 1) + j0 - (i0w + 15);
        #pragma unroll
        for (int ks = 0; ks < 2; ++ks)
            #pragma unroll
            for (int cb = 0; cb < 5; ++cb) {
                int p = pw0 + 16 * cb + row16;
                p = p > (L - 1) ? (L - 1) : p;     // clamped rows feed masked cols only
                bf16x8 rf = *reinterpret_cast<const bf16x8*>(
                    rkb + (size_t)p * DH + kgrp * 8 + ks * 32);
                db[cb] = __builtin_amdgcn_mfma_f32_16x16x32_bf16(qrf[ks], rf, db[cb], 0, 0, 0);
            }

        // ---- softmax (fixed m=0) with in-register shift ----
        #pragma unroll
        for (int r = 0; r < 4; ++r) {
            const int ri = kgrp * 4 + r;
            const int i_glob = i0w + ri;
            const int u  = row16 + 15 - ri;        // 0..30
            const int lo = u & 15;
            const int hi = u >> 4;
            const int srclane = (lane & 48) | lo;
            float T[5];
            #pragma unroll
            for (int c2 = 0; c2 < 5; ++c2)
                T[c2] = __shfl(db[c2][r], srclane, 64);
            float rsum = 0.f;
            #pragma unroll
            for (int cb = 0; cb < 4; ++cb) {
                const int jj = 16 * cb + row16;
                float bd = hi ? T[cb + 1] : T[cb];
                float s = SCALE_F * (ac[cb][r] + bd);
                if (j0 + jj > i_glob) s = -INFINITY;
                float p = __expf(s);
                pt[w][ri][jj] = (__bf16)p;
                rsum += p;
            }
            #pragma unroll
            for (int off = 1; off < 16; off <<= 1)
                rsum += __shfl_xor(rsum, off);
            l_run[r] += rsum;
        }

        // ---- O += P · V ----
        #pragma unroll
        for (int ks = 0; ks < 2; ++ks) {
            bf16x8 pf = *reinterpret_cast<const bf16x8*>(&pt[w][row16][kgrp * 8 + ks * 32]);
            #pragma unroll
            for (int cb = 0; cb < 4; ++cb) {
                bf16x8 vf = *reinterpret_cast<const bf16x8*>(&vtT[16 * cb + row16][kgrp * 8 + ks * 32]);
                O[cb] = __builtin_amdgcn_mfma_f32_16x16x32_bf16(pf, vf, O[cb], 0, 0, 0);
            }
        }
    }

    // ---- accumulate partials: O rows into P[bh][it][row*64+col], l into +4096 ----
    float* Pb = P + ((size_t)bh * 32 + it) * PSLOT;
    #pragma unroll
    for (int r = 0; r < 4; ++r) {
        const int row = w * 16 + kgrp * 4 + r;
        #pragma unroll
        for (int cb = 0; cb < 4; ++cb)
            atomicAdd(&Pb[row * 64 + 16 * cb + row16], O[cb][r]);
        if (row16 == 0)
            atomicAdd(&Pb[4096 + row], l_run[r]);
    }
}

// ---------------------------------------------------------------------------
// Combine partials: av = O_sum / l_sum, bf16, attn_vec layout.
// ---------------------------------------------------------------------------
__global__ __launch_bounds__(256)
void attn_reduce(const float* __restrict__ P, __bf16* __restrict__ av)
{
    const int bh = blockIdx.y;
    const int it = blockIdx.x;
    const int n = bh & (NH - 1), b = bh >> 4;
    const float* Pb = P + ((size_t)bh * 32 + it) * PSLOT;
    const int t = threadIdx.x;
    const int row = t >> 2;
    const int c0 = (t & 3) * 16;
    const float inv = 1.0f / Pb[4096 + row];
    const int i_glob = it * 64 + row;
    __bf16* dst = av + (size_t)(i_glob * BSZ + b) * (NH * DH) + n * DH + c0;
    #pragma unroll
    for (int v4 = 0; v4 < 4; ++v4) {
        float4 o = *reinterpret_cast<const float4*>(&Pb[row * 64 + c0 + v4 * 4]);
        bf16x4 ov = { (__bf16)(o.x * inv), (__bf16)(o.y * inv),
                      (__bf16)(o.z * inv), (__bf16)(o.w * inv) };
        *reinterpret_cast<bf16x4*>(dst + v4 * 4) = ov;
    }
}

// ---------------------------------------------------------------------------
// Fused residual + LayerNorm
// ---------------------------------------------------------------------------
__global__ __launch_bounds__(256)
void ln_fused(const float* __restrict__ w, const float* __restrict__ ao,
              const float* __restrict__ g, const float* __restrict__ bb,
              float* __restrict__ out)
{
    const int row = blockIdx.x;
    const float* wr = w  + (size_t)row * DM;
    const float* ar = ao + (size_t)row * DM;
    const int t = threadIdx.x;
    float x[4];
    float s = 0.f;
    #pragma unroll
    for (int j = 0; j < 4; ++j) {
        int c = t + j * 256;
        x[j] = wr[c] + ar[c];
        s += x[j];
    }
    __shared__ float red[4];
    #pragma unroll
    for (int off = 1; off < 64; off <<= 1) s += __shfl_xor(s, off);
    int wid = t >> 6, lane = t & 63;
    if (lane == 0) red[wid] = s;
    __syncthreads();
    float mu = (red[0] + red[1] + red[2] + red[3]) * (1.0f / DM);
    float ss = 0.f;
    #pragma unroll
    for (int j = 0; j < 4; ++j) { float d = x[j] - mu; ss += d * d; }
    #pragma unroll
    for (int off = 1; off < 64; off <<= 1) ss += __shfl_xor(ss, off);
    __syncthreads();
    if (lane == 0) red[wid] = ss;
    __syncthreads();
    float var = (red[0] + red[1] + red[2] + red[3]) * (1.0f / DM);
    float rstd = rsqrtf(var + 1e-5f);
    #pragma unroll
    for (int j = 0; j < 4; ++j) {
        int c = t + j * 256;
        out[(size_t)row * DM + c] = (x[j] - mu) * rstd * g[c] + bb[c];
    }
}

extern "C" void kernel_launch(void* const* d_in, const int* in_sizes, int n_in,
                              void* d_out, int out_size, void* d_ws, size_t ws_size,
                              hipStream_t stream)
{
    (void)in_sizes; (void)n_in; (void)out_size; (void)ws_size;
    const float* w   = (const float*)d_in[0];
    const float* r   = (const float*)d_in[1];
    const float* rwb = (const float*)d_in[2];
    const float* rrb = (const float*)d_in[3];
    const float* Wq  = (const float*)d_in[4];
    const float* bq  = (const float*)d_in[5];
    const float* Wk  = (const float*)d_in[6];
    const float* bk  = (const float*)d_in[7];
    const float* Wv  = (const float*)d_in[8];
    const float* bv  = (const float*)d_in[9];
    const float* Wr  = (const float*)d_in[10];
    const float* br  = (const float*)d_in[11];
    const float* Wo  = (const float*)d_in[12];
    const float* bo  = (const float*)d_in[13];
    const float* lng = (const float*)d_in[14];
    const float* lnb = (const float*)d_in[15];
    float* out = (float*)d_out;

    const size_t NQ = (size_t)BSZ * NH * L * DH;   // 4.19M
    const size_t PN = (size_t)BSZ * NH * 32 * PSLOT;  // 4.26M f32 partial buffer
    char* wsb = (char*)d_ws;
    __bf16* w_bf    = (__bf16*)wsb;  wsb += (size_t)2 * L * DM * 2;
    __bf16* r_bf    = (__bf16*)wsb;  wsb += (size_t)L * DM * 2;
    __bf16* wqkv_t  = (__bf16*)wsb;  wsb += (size_t)3 * DM * DM * 2;
    __bf16* wr_t    = (__bf16*)wsb;  wsb += (size_t)DM * DM * 2;
    __bf16* wo_t    = (__bf16*)wsb;  wsb += (size_t)DM * DM * 2;
    __bf16* qw_ws   = (__bf16*)wsb;  wsb += NQ * 2;
    __bf16* qr_ws   = (__bf16*)wsb;  wsb += NQ * 2;
    __bf16* k_ws    = (__bf16*)wsb;  wsb += NQ * 2;
    __bf16* v_ws    = (__bf16*)wsb;  wsb += NQ * 2;
    __bf16* rk_ws   = (__bf16*)wsb;  wsb += (size_t)NH * L * DH * 2;
    __bf16* av_ws   = (__bf16*)wsb;  wsb += NQ * 2;
    float*  P_ws    = (float*)wsb;   // PN floats; ao_ws ALIASES this region:
    float*  ao_ws   = P_ws;          // P consumed by attn_reduce before o-proj writes ao

    dim3 blk(256);
    // zero partial accumulators (capture-legal async memset)
    hipMemsetAsync(P_ws, 0, PN * sizeof(float), stream);

    cast2_f32_bf16<<<dim3(1536), blk, 0, stream>>>(
        w, (2 * L * DM) / 4, r, (L * DM) / 4, w_bf, r_bf);
    transpose_w5<<<dim3(32, 32, 5), blk, 0, stream>>>(
        Wq, Wk, Wv, Wr, Wo,
        wqkv_t, wqkv_t + (size_t)DM * DM, wqkv_t + (size_t)2 * DM * DM, wr_t, wo_t);

    // fused QKV (768 blocks) + RK (128 blocks -> o4/b3)
    gemm_bf16<<<dim3(896), blk, 0, stream>>>(w_bf, r_bf, wqkv_t, wr_t, 0,
        qw_ws, qr_ws, k_ws, v_ws, rk_ws, bq, bk, bv, br, rwb, rrb, nullptr);

    // flash-decoding attention: partials + reduce
    attn_partial<<<dim3(80, BSZ * NH), blk, 0, stream>>>(
        qw_ws, qr_ws, k_ws, v_ws, rk_ws, P_ws);
    attn_reduce<<<dim3(32, BSZ * NH), blk, 0, stream>>>(P_ws, av_ws);

    // output projection -> fp32 (overwrites P region, already consumed)
    gemm_bf16<<<dim3(32, 8), blk, 0, stream>>>(av_ws, nullptr, wo_t, nullptr, 1,
        nullptr, nullptr, nullptr, nullptr, nullptr, bo, nullptr, nullptr, nullptr,
        nullptr, nullptr, ao_ws);

    ln_fused<<<dim3(L * BSZ), blk, 0, stream>>>(w, ao_ws, lng, lnb, out);
}